// Round 12
// baseline (318.466 us; speedup 1.0000x reference)
//
#include <hip/hip_runtime.h>
#include <cstdint>

// ---------------------------------------------------------------------------
// AttentionSelector: selected = softmax(query @ (x@Wk^T+bk)^T) @ x
// R12: flash frozen at its structural plateau (37% dense MFMA, 7 variants
//      187-216us; breaking it needs hand-asm interleave per m131-m141).
//      Harvest dispatch overhead instead: COMBINE FUSED INTO FLASH via the
//      split-K completion pattern — per-qb device-scope counter; the last of
//      the 16 ns-blocks normalizes its 256 queries in-kernel. Deletes the
//      combine dispatch + its full-GPU drain gap; 31/32 winners are hidden
//      under remaining flash work. Cross-XCD visibility: __syncthreads
//      (vmcnt drain) + __threadfence + device-scope atomicAdd (G16).
//      Counters zeroed by 128-B hipMemsetAsync (graph-legal).
//      Prep: R11 (mfma query-side, ones-trick) with the zero-fill fixed.
// ---------------------------------------------------------------------------

typedef __bf16    bf16x4 __attribute__((ext_vector_type(4)));
typedef __bf16    bf16x8 __attribute__((ext_vector_type(8)));
typedef _Float16  f16x4  __attribute__((ext_vector_type(4)));
typedef _Float16  f16x8  __attribute__((ext_vector_type(8)));
typedef float     f32x2  __attribute__((ext_vector_type(2)));
typedef float     f32x16 __attribute__((ext_vector_type(16)));

extern "C" __device__ float __ocml_native_exp2_f32(float);

#define NUM_PAIRS   65536
#define NUM_Q       8192
#define DIM         66
#define QPITCH      80        // Qh row pitch (f16)
#define KFT         2560      // Af f16 per 32-pair tile (5 kk x 512)
#define XFT         3072      // Xf bf16 per 32-pair tile (6 c x 512)
#define PARTP       68        // partial row pitch (floats)
#define NS          16
#define NTILES      (NUM_PAIRS/32)   // 2048

__device__ __forceinline__ f32x16 mfma_bf16(bf16x8 a, bf16x8 b, f32x16 c) {
    return __builtin_amdgcn_mfma_f32_32x32x16_bf16(a, b, c, 0, 0, 0);
}
__device__ __forceinline__ f32x16 mfma_f16(f16x8 a, f16x8 b, f32x16 c) {
    return __builtin_amdgcn_mfma_f32_32x32x16_f16(a, b, c, 0, 0, 0);
}
// gfx950: exchange lanes 32..63 of a with lanes 0..31 of b.
__device__ __forceinline__ void plswap(unsigned &a, unsigned &b) {
    asm("v_permlane32_swap_b32 %0, %1" : "+v"(a), "+v"(b));
}
__device__ __forceinline__ unsigned packbf(float a, float b) {
    union { __bf16 h[2]; unsigned u; } t;
    t.h[0] = (__bf16)a; t.h[1] = (__bf16)b;
    return t.u;
}
union U4 { unsigned u[4]; bf16x8 v; };

// Sᵀ C-tile (col=query l31, row(pair)=(r&3)+8*(r>>2)+4h) -> exp2 -> two PV
// A-frags (par0: pairs 0..15, par1: 16..31) via permlane32_swap (verified R2-R11).
__device__ __forceinline__ void makefrags(const f32x16 &s, U4 *f) {
    float P[16];
    #pragma unroll
    for (int r = 0; r < 16; ++r) P[r] = __ocml_native_exp2_f32(s[r]);
    unsigned E0 = packbf(P[0],  P[1]),  E1 = packbf(P[2],  P[3]);
    unsigned F0 = packbf(P[4],  P[5]),  F1 = packbf(P[6],  P[7]);
    plswap(E0, F0); plswap(E1, F1);
    f[0].u[0] = E0; f[0].u[1] = E1; f[0].u[2] = F0; f[0].u[3] = F1;
    unsigned G0 = packbf(P[8],  P[9]),  G1 = packbf(P[10], P[11]);
    unsigned H0 = packbf(P[12], P[13]), H1 = packbf(P[14], P[15]);
    plswap(G0, H0); plswap(G1, H1);
    f[1].u[0] = G0; f[1].u[1] = G1; f[1].u[2] = H0; f[1].u[3] = H1;
}

// One pipelined flash step for tile t (verified R10/R11).
__device__ __forceinline__ void pipe_step(
    int t, int tiles, const _Float16* __restrict__ kf, const __bf16* __restrict__ xf,
    f16x8 (&kPre)[5], const f16x8 (&kNext)[5], bf16x8 (&xR)[6],
    const f16x8 (&aQ)[2][5], f32x16 &s0, f32x16 &s1, f32x16 (&o)[2][3]) {

    {   // prefetch k(t+2) into the dead buffer
        long tk = (t + 2 < tiles) ? (long)(t + 2) : (long)(tiles - 1);
        const _Float16* kp = kf + tk * KFT;
        #pragma unroll
        for (int kk = 0; kk < 5; ++kk) kPre[kk] = *(const f16x8*)(kp + kk * 512);
    }
    U4 f0[2];
    makefrags(s0, f0);
    {
        f32x16 ns = {};
        #pragma unroll
        for (int kk = 0; kk < 5; ++kk) ns = mfma_f16(kNext[kk], aQ[0][kk], ns);
        s0 = ns;
    }
    #pragma unroll
    for (int par = 0; par < 2; ++par)
        #pragma unroll
        for (int dt = 0; dt < 3; ++dt)
            o[0][dt] = mfma_bf16(f0[par].v, xR[par * 3 + dt], o[0][dt]);

    U4 f1[2];
    makefrags(s1, f1);
    {
        f32x16 ns = {};
        #pragma unroll
        for (int kk = 0; kk < 5; ++kk) ns = mfma_f16(kNext[kk], aQ[1][kk], ns);
        s1 = ns;
    }
    #pragma unroll
    for (int par = 0; par < 2; ++par)
        #pragma unroll
        for (int dt = 0; dt < 3; ++dt)
            o[1][dt] = mfma_bf16(f1[par].v, xR[par * 3 + dt], o[1][dt]);

    {   // reload x with tile t+1 (last use was PV1 above)
        long tx = (t + 1 < tiles) ? (long)(t + 1) : (long)(tiles - 1);
        const __bf16* xp = xf + tx * XFT;
        #pragma unroll
        for (int c = 0; c < 6; ++c) xR[c] = *(const bf16x8*)(xp + c * 512);
    }
}

// ---------------------------------------------------------------------------
// Prep: blocks 0..511 -> 128 pairs each: x -> Af (f16 S-frags) + Xf (bf16 PV
//       frags, ones-trick for row 66). blocks 512..575 -> 128 queries each:
//       Qh = (Wk^T q)*log2e via mfma f16.
// ---------------------------------------------------------------------------
#define PAP 104   // LDS pitch (f16)
__global__ __launch_bounds__(256) void prep_kernel(
    const float* __restrict__ x, const float* __restrict__ query,
    const float* __restrict__ Wk,
    unsigned short* __restrict__ Af_u, unsigned short* __restrict__ Xf_u,
    unsigned short* __restrict__ Qh_u) {
    const int tid = threadIdx.x;
    const int lane = tid & 63, w = tid >> 6;
    const int l31 = lane & 31, h = lane >> 5;

    if (blockIdx.x >= 512) {
        // ---- query side: Qh = (Wk^T q) * log2e via mfma ----
        __shared__ _Float16 sq[128 * PAP];    // query rows f16, pads 0
        __shared__ _Float16 sWT[96 * PAP];    // sWT[e][d] = Wk[d][e]*log2e, pads 0
        _Float16* Qh = (_Float16*)Qh_u;
        const long q0 = (long)(blockIdx.x - 512) * 128;

        for (int i = tid; i < 128 * PAP / 2; i += 256) ((unsigned*)sq)[i] = 0u;
        for (int i = tid; i < 96 * PAP / 2; i += 256)  ((unsigned*)sWT)[i] = 0u;
        __syncthreads();

        for (int i = tid; i < 128 * 33; i += 256) {       // f32x2 loads
            int r = i / 33, c2 = (i % 33) * 2;
            f32x2 v = *(const f32x2*)&query[(q0 + r) * DIM + c2];
            sq[r * PAP + c2]     = (_Float16)v.x;
            sq[r * PAP + c2 + 1] = (_Float16)v.y;
        }
        for (int i = tid; i < DIM * 33; i += 256) {       // Wk transposed, scaled
            int d = i / 33, e2 = (i % 33) * 2;
            f32x2 v = *(const f32x2*)&Wk[d * DIM + e2];
            sWT[e2 * PAP + d]       = (_Float16)(v.x * 1.4426950408889634f);
            sWT[(e2 + 1) * PAP + d] = (_Float16)(v.y * 1.4426950408889634f);
        }
        __syncthreads();

        #pragma unroll
        for (int nt = 0; nt < 3; ++nt) {
            f32x16 acc = {};
            #pragma unroll
            for (int kk = 0; kk < 6; ++kk) {
                f16x8 a = *(const f16x8*)&sq[(w * 32 + l31) * PAP + kk * 16 + h * 8];
                f16x8 b = *(const f16x8*)&sWT[(nt * 32 + l31) * PAP + kk * 16 + h * 8];
                acc = mfma_f16(a, b, acc);
            }
            int c = nt * 32 + l31;
            if (c < QPITCH) {
                #pragma unroll
                for (int r = 0; r < 16; ++r) {
                    int row = (r & 3) + 8 * (r >> 2) + 4 * h;
                    Qh[(q0 + w * 32 + row) * QPITCH + c] = (_Float16)acc[r];
                }
            }
        }
        return;
    }

    // ---- pair side: x -> Af + Xf ----
    _Float16* Af = (_Float16*)Af_u;
    __bf16*   Xf = (__bf16*)Xf_u;
    __shared__ _Float16 sxh[128 * PAP];   // cols: 0..65 = x, 66 = 1.0, 67.. = 0
    const long n0 = (long)blockIdx.x * 128;

    for (int i = tid; i < 128 * PAP / 2; i += 256) ((unsigned*)sxh)[i] = 0u;
    __syncthreads();
    for (int i = tid; i < 128 * 33; i += 256) {
        int r = i / 33, c2 = (i % 33) * 2;
        f32x2 v = *(const f32x2*)&x[(n0 + r) * DIM + c2];
        sxh[r * PAP + c2]     = (_Float16)v.x;
        sxh[r * PAP + c2 + 1] = (_Float16)v.y;
    }
    for (int r = tid; r < 128; r += 256) sxh[r * PAP + DIM] = (_Float16)1.0f;
    __syncthreads();

    // Af emission: [tile][kk][lane][8] (col 66 = 1 harmless: Qh cols 66+ are 0)
    for (int i = 0; i < 5; ++i) {
        int slot = i * 256 + tid;
        int tt = slot / 320, rem = slot % 320;
        int kk = rem / 64, l = rem % 64;
        const _Float16* src = &sxh[(32 * tt + (l & 31)) * PAP + kk * 16 + (l >> 5) * 8];
        f16x4 lo = *(const f16x4*)src;
        f16x4 hi = *(const f16x4*)(src + 4);
        f16x8 v = __builtin_shufflevector(lo, hi, 0, 1, 2, 3, 4, 5, 6, 7);
        *(f16x8*)&Af[((long)blockIdx.x * 4 + tt) * KFT + kk * 512 + l * 8] = v;
    }
    // Xf emission (branch-free): [tile][c=par*3+dt][lane][8] = X^T[d][pair]
    for (int i = 0; i < 6; ++i) {
        int slot = i * 256 + tid;
        int tt = slot / 384, rem = slot % 384;
        int c = rem / 64, l = rem % 64;
        int dt = c % 3, par = c / 3;
        int d = 32 * dt + (l & 31);
        int p0 = 32 * tt + 16 * par + 8 * (l >> 5);
        bf16x8 v;
        #pragma unroll
        for (int j = 0; j < 8; ++j)
            v[j] = (__bf16)(float)sxh[(p0 + j) * PAP + d];
        *(bf16x8*)&Xf[((long)blockIdx.x * 4 + tt) * XFT + c * 512 + l * 8] = v;
    }
}

// ---------------------------------------------------------------------------
// Flash + fused combine: grid = 32 qblocks * NS; 256 thr = 4 waves x 64 q.
// Streaming K-loop (R10). Epilogue: write Part slice, then split-K completion
// — last ns-block for this qb normalizes its 256 queries and writes out.
// ---------------------------------------------------------------------------
__global__ __launch_bounds__(256, 2) void flash_kernel(
    const unsigned short* __restrict__ Qh_u, const unsigned short* __restrict__ Af_u,
    const unsigned short* __restrict__ Xf_u, float* __restrict__ Part,
    unsigned* __restrict__ Cnt, float* __restrict__ out) {
    const _Float16* Qh = (const _Float16*)Qh_u;
    const _Float16* Af = (const _Float16*)Af_u;
    const __bf16*   Xf = (const __bf16*)Xf_u;

    const int tid = threadIdx.x;
    const int lane = tid & 63, wave = tid >> 6;
    const int l31 = lane & 31, h = lane >> 5;
    const int qb = blockIdx.x / NS, ns = blockIdx.x % NS;
    const int tiles = NTILES / NS;            // 128
    const int qbase = qb * 256 + wave * 64;

    const _Float16* kf = Af + (long)(ns * tiles) * KFT + lane * 8;
    const __bf16*   xf = Xf + (long)(ns * tiles) * XFT + lane * 8;

    f16x8 aQ[2][5];
    #pragma unroll
    for (int qt = 0; qt < 2; ++qt)
        #pragma unroll
        for (int kk = 0; kk < 5; ++kk)
            aQ[qt][kk] = *(const f16x8*)&Qh[(long)(qbase + qt * 32 + l31) * QPITCH + kk * 16 + h * 8];

    f32x16 o[2][3] = {};
    f16x8  kA[5], kB[5];
    bf16x8 xR[6];
    f32x16 s0, s1;

    #pragma unroll
    for (int kk = 0; kk < 5; ++kk) kA[kk] = *(const f16x8*)(kf + kk * 512);
    #pragma unroll
    for (int c = 0; c < 6; ++c)    xR[c]  = *(const bf16x8*)(xf + c * 512);
    #pragma unroll
    for (int kk = 0; kk < 5; ++kk) kB[kk] = *(const f16x8*)(kf + KFT + kk * 512);
    {
        f32x16 a = {}, b = {};
        #pragma unroll
        for (int kk = 0; kk < 5; ++kk) {
            a = mfma_f16(kA[kk], aQ[0][kk], a);
            b = mfma_f16(kA[kk], aQ[1][kk], b);
        }
        s0 = a; s1 = b;
    }

    for (int t = 0; t < tiles; t += 2) {
        pipe_step(t,     tiles, kf, xf, kA, kB, xR, aQ, s0, s1, o);
        pipe_step(t + 1, tiles, kf, xf, kB, kA, xR, aQ, s0, s1, o);
    }

    // ---- epilogue: Part slice [q][ns][68]; col 66 = denominator ----
    #pragma unroll
    for (int qt = 0; qt < 2; ++qt)
        #pragma unroll
        for (int dt = 0; dt < 3; ++dt)
            #pragma unroll
            for (int r = 0; r < 16; ++r) {
                int row = (r & 3) + 8 * (r >> 2) + 4 * h;
                int q = qbase + qt * 32 + row;
                int d = dt * 32 + l31;
                if (d < DIM + 1)
                    Part[((long)q * NS + ns) * PARTP + d] = o[qt][dt][r];
            }

    // ---- split-K completion: last ns-block for this qb combines ----
    __shared__ unsigned sdone;
    __shared__ float srden[256];
    __syncthreads();                      // drains all Part stores (vmcnt 0)
    if (tid == 0) {
        __threadfence();                  // release: Part visible device-wide
        unsigned prev = atomicAdd(&Cnt[qb], 1u);
        sdone = (prev == NS - 1) ? 1u : 0u;
    }
    __syncthreads();
    if (!sdone) return;
    __threadfence();                      // acquire: see all writers

    const int q0 = qb * 256;
    {   // phase 1: reciprocal denominators for 256 queries
        const float* bp = Part + ((long)(q0 + tid) * NS) * PARTP + DIM;
        float den = 0.f;
        #pragma unroll
        for (int s = 0; s < NS; ++s) den += bp[s * PARTP];
        srden[tid] = 1.f / den;
    }
    __syncthreads();
    // phase 2: outputs
    for (int i = tid; i < 256 * DIM; i += 256) {
        int qi = i / DIM, d = i - qi * DIM;
        const float* bp = Part + ((long)(q0 + qi) * NS) * PARTP + d;
        float num = 0.f;
        #pragma unroll
        for (int s = 0; s < NS; ++s) num += bp[s * PARTP];
        out[(long)(q0 + qi) * DIM + d] = num * srden[qi];
    }
}

// ---------------------------------------------------------------------------
// Workspace: Qh @0 (1,310,720 B) ; Af @1,310,720 (10,485,760 B) ;
//            Xf @11,796,480 (12,582,912 B) ; Part @24,379,392 (35,651,584 B) ;
//            Cnt @60,030,976 (128 B)
// ---------------------------------------------------------------------------
extern "C" void kernel_launch(void* const* d_in, const int* in_sizes, int n_in,
                              void* d_out, int out_size, void* d_ws, size_t ws_size,
                              hipStream_t stream) {
    const float* x     = (const float*)d_in[0];
    const float* query = (const float*)d_in[1];
    const float* Wk    = (const float*)d_in[2];
    float* out = (float*)d_out;
    char* ws = (char*)d_ws;

    unsigned short* Qh = (unsigned short*)(ws + 0);
    unsigned short* Af = (unsigned short*)(ws + 1310720);
    unsigned short* Xf = (unsigned short*)(ws + 11796480);
    float* Part        = (float*)(ws + 24379392);
    unsigned* Cnt      = (unsigned*)(ws + 60030976);

    hipMemsetAsync(Cnt, 0, 128, stream);
    prep_kernel<<<512 + NUM_Q / 128, 256, 0, stream>>>(x, query, Wk, Af, Xf, Qh);
    flash_kernel<<<(NUM_Q / 256) * NS, 256, 0, stream>>>(Qh, Af, Xf, Part, Cnt, out);
}

// Round 13
// 262.473 us; speedup vs baseline: 1.2133x; 1.2133x over previous
//
#include <hip/hip_runtime.h>
#include <cstdint>

// ---------------------------------------------------------------------------
// AttentionSelector: selected = softmax(query @ (x@Wk^T+bk)^T) @ x
// R13: revert R12's fused combine (last-block completion concentrated 35MB of
//      Part reads on 32 tail blocks with 224 CUs idle -> +45us). Back to the
//      R11 3-dispatch spine, with Part stored in BF16 (halves the partial
//      stream: flash writes 17.8MB instead of 35.6, combine reads halve).
//      Accuracy: bf16 partial rounding adds <=~0.012 abs err vs 0.056 margin.
//      flash (R10 streaming K-loop) + prep (R11 mfma query-side) unchanged.
// ---------------------------------------------------------------------------

typedef __bf16    bf16x4 __attribute__((ext_vector_type(4)));
typedef __bf16    bf16x8 __attribute__((ext_vector_type(8)));
typedef _Float16  f16x4  __attribute__((ext_vector_type(4)));
typedef _Float16  f16x8  __attribute__((ext_vector_type(8)));
typedef float     f32x2  __attribute__((ext_vector_type(2)));
typedef float     f32x16 __attribute__((ext_vector_type(16)));

extern "C" __device__ float __ocml_native_exp2_f32(float);

#define NUM_PAIRS   65536
#define NUM_Q       8192
#define DIM         66
#define QPITCH      80        // Qh row pitch (f16)
#define KFT         2560      // Af f16 per 32-pair tile (5 kk x 512)
#define XFT         3072      // Xf bf16 per 32-pair tile (6 c x 512)
#define PARTP       68        // partial row pitch (bf16)
#define NS          16
#define NTILES      (NUM_PAIRS/32)   // 2048

__device__ __forceinline__ f32x16 mfma_bf16(bf16x8 a, bf16x8 b, f32x16 c) {
    return __builtin_amdgcn_mfma_f32_32x32x16_bf16(a, b, c, 0, 0, 0);
}
__device__ __forceinline__ f32x16 mfma_f16(f16x8 a, f16x8 b, f32x16 c) {
    return __builtin_amdgcn_mfma_f32_32x32x16_f16(a, b, c, 0, 0, 0);
}
// gfx950: exchange lanes 32..63 of a with lanes 0..31 of b.
__device__ __forceinline__ void plswap(unsigned &a, unsigned &b) {
    asm("v_permlane32_swap_b32 %0, %1" : "+v"(a), "+v"(b));
}
__device__ __forceinline__ unsigned packbf(float a, float b) {
    union { __bf16 h[2]; unsigned u; } t;
    t.h[0] = (__bf16)a; t.h[1] = (__bf16)b;
    return t.u;
}
union U4 { unsigned u[4]; bf16x8 v; };

// Sᵀ C-tile (col=query l31, row(pair)=(r&3)+8*(r>>2)+4h) -> exp2 -> two PV
// A-frags (par0: pairs 0..15, par1: 16..31) via permlane32_swap (verified R2-R12).
__device__ __forceinline__ void makefrags(const f32x16 &s, U4 *f) {
    float P[16];
    #pragma unroll
    for (int r = 0; r < 16; ++r) P[r] = __ocml_native_exp2_f32(s[r]);
    unsigned E0 = packbf(P[0],  P[1]),  E1 = packbf(P[2],  P[3]);
    unsigned F0 = packbf(P[4],  P[5]),  F1 = packbf(P[6],  P[7]);
    plswap(E0, F0); plswap(E1, F1);
    f[0].u[0] = E0; f[0].u[1] = E1; f[0].u[2] = F0; f[0].u[3] = F1;
    unsigned G0 = packbf(P[8],  P[9]),  G1 = packbf(P[10], P[11]);
    unsigned H0 = packbf(P[12], P[13]), H1 = packbf(P[14], P[15]);
    plswap(G0, H0); plswap(G1, H1);
    f[1].u[0] = G0; f[1].u[1] = G1; f[1].u[2] = H0; f[1].u[3] = H1;
}

// One pipelined flash step for tile t (verified R10/R11).
__device__ __forceinline__ void pipe_step(
    int t, int tiles, const _Float16* __restrict__ kf, const __bf16* __restrict__ xf,
    f16x8 (&kPre)[5], const f16x8 (&kNext)[5], bf16x8 (&xR)[6],
    const f16x8 (&aQ)[2][5], f32x16 &s0, f32x16 &s1, f32x16 (&o)[2][3]) {

    {   // prefetch k(t+2) into the dead buffer
        long tk = (t + 2 < tiles) ? (long)(t + 2) : (long)(tiles - 1);
        const _Float16* kp = kf + tk * KFT;
        #pragma unroll
        for (int kk = 0; kk < 5; ++kk) kPre[kk] = *(const f16x8*)(kp + kk * 512);
    }
    U4 f0[2];
    makefrags(s0, f0);
    {
        f32x16 ns = {};
        #pragma unroll
        for (int kk = 0; kk < 5; ++kk) ns = mfma_f16(kNext[kk], aQ[0][kk], ns);
        s0 = ns;
    }
    #pragma unroll
    for (int par = 0; par < 2; ++par)
        #pragma unroll
        for (int dt = 0; dt < 3; ++dt)
            o[0][dt] = mfma_bf16(f0[par].v, xR[par * 3 + dt], o[0][dt]);

    U4 f1[2];
    makefrags(s1, f1);
    {
        f32x16 ns = {};
        #pragma unroll
        for (int kk = 0; kk < 5; ++kk) ns = mfma_f16(kNext[kk], aQ[1][kk], ns);
        s1 = ns;
    }
    #pragma unroll
    for (int par = 0; par < 2; ++par)
        #pragma unroll
        for (int dt = 0; dt < 3; ++dt)
            o[1][dt] = mfma_bf16(f1[par].v, xR[par * 3 + dt], o[1][dt]);

    {   // reload x with tile t+1 (last use was PV1 above)
        long tx = (t + 1 < tiles) ? (long)(t + 1) : (long)(tiles - 1);
        const __bf16* xp = xf + tx * XFT;
        #pragma unroll
        for (int c = 0; c < 6; ++c) xR[c] = *(const bf16x8*)(xp + c * 512);
    }
}

// ---------------------------------------------------------------------------
// Prep: blocks 0..511 -> 128 pairs each: x -> Af (f16 S-frags) + Xf (bf16 PV
//       frags, ones-trick for row 66). blocks 512..575 -> 128 queries each:
//       Qh = (Wk^T q)*log2e via mfma f16.
// ---------------------------------------------------------------------------
#define PAP 104   // LDS pitch (f16)
__global__ __launch_bounds__(256) void prep_kernel(
    const float* __restrict__ x, const float* __restrict__ query,
    const float* __restrict__ Wk,
    unsigned short* __restrict__ Af_u, unsigned short* __restrict__ Xf_u,
    unsigned short* __restrict__ Qh_u) {
    const int tid = threadIdx.x;
    const int lane = tid & 63, w = tid >> 6;
    const int l31 = lane & 31, h = lane >> 5;

    if (blockIdx.x >= 512) {
        // ---- query side: Qh = (Wk^T q) * log2e via mfma ----
        __shared__ _Float16 sq[128 * PAP];    // query rows f16, pads 0
        __shared__ _Float16 sWT[96 * PAP];    // sWT[e][d] = Wk[d][e]*log2e, pads 0
        _Float16* Qh = (_Float16*)Qh_u;
        const long q0 = (long)(blockIdx.x - 512) * 128;

        for (int i = tid; i < 128 * PAP / 2; i += 256) ((unsigned*)sq)[i] = 0u;
        for (int i = tid; i < 96 * PAP / 2; i += 256)  ((unsigned*)sWT)[i] = 0u;
        __syncthreads();

        for (int i = tid; i < 128 * 33; i += 256) {       // f32x2 loads
            int r = i / 33, c2 = (i % 33) * 2;
            f32x2 v = *(const f32x2*)&query[(q0 + r) * DIM + c2];
            sq[r * PAP + c2]     = (_Float16)v.x;
            sq[r * PAP + c2 + 1] = (_Float16)v.y;
        }
        for (int i = tid; i < DIM * 33; i += 256) {       // Wk transposed, scaled
            int d = i / 33, e2 = (i % 33) * 2;
            f32x2 v = *(const f32x2*)&Wk[d * DIM + e2];
            sWT[e2 * PAP + d]       = (_Float16)(v.x * 1.4426950408889634f);
            sWT[(e2 + 1) * PAP + d] = (_Float16)(v.y * 1.4426950408889634f);
        }
        __syncthreads();

        #pragma unroll
        for (int nt = 0; nt < 3; ++nt) {
            f32x16 acc = {};
            #pragma unroll
            for (int kk = 0; kk < 6; ++kk) {
                f16x8 a = *(const f16x8*)&sq[(w * 32 + l31) * PAP + kk * 16 + h * 8];
                f16x8 b = *(const f16x8*)&sWT[(nt * 32 + l31) * PAP + kk * 16 + h * 8];
                acc = mfma_f16(a, b, acc);
            }
            int c = nt * 32 + l31;
            if (c < QPITCH) {
                #pragma unroll
                for (int r = 0; r < 16; ++r) {
                    int row = (r & 3) + 8 * (r >> 2) + 4 * h;
                    Qh[(q0 + w * 32 + row) * QPITCH + c] = (_Float16)acc[r];
                }
            }
        }
        return;
    }

    // ---- pair side: x -> Af + Xf ----
    _Float16* Af = (_Float16*)Af_u;
    __bf16*   Xf = (__bf16*)Xf_u;
    __shared__ _Float16 sxh[128 * PAP];   // cols: 0..65 = x, 66 = 1.0, 67.. = 0
    const long n0 = (long)blockIdx.x * 128;

    for (int i = tid; i < 128 * PAP / 2; i += 256) ((unsigned*)sxh)[i] = 0u;
    __syncthreads();
    for (int i = tid; i < 128 * 33; i += 256) {
        int r = i / 33, c2 = (i % 33) * 2;
        f32x2 v = *(const f32x2*)&x[(n0 + r) * DIM + c2];
        sxh[r * PAP + c2]     = (_Float16)v.x;
        sxh[r * PAP + c2 + 1] = (_Float16)v.y;
    }
    for (int r = tid; r < 128; r += 256) sxh[r * PAP + DIM] = (_Float16)1.0f;
    __syncthreads();

    // Af emission: [tile][kk][lane][8] (col 66 = 1 harmless: Qh cols 66+ are 0)
    for (int i = 0; i < 5; ++i) {
        int slot = i * 256 + tid;
        int tt = slot / 320, rem = slot % 320;
        int kk = rem / 64, l = rem % 64;
        const _Float16* src = &sxh[(32 * tt + (l & 31)) * PAP + kk * 16 + (l >> 5) * 8];
        f16x4 lo = *(const f16x4*)src;
        f16x4 hi = *(const f16x4*)(src + 4);
        f16x8 v = __builtin_shufflevector(lo, hi, 0, 1, 2, 3, 4, 5, 6, 7);
        *(f16x8*)&Af[((long)blockIdx.x * 4 + tt) * KFT + kk * 512 + l * 8] = v;
    }
    // Xf emission (branch-free): [tile][c=par*3+dt][lane][8] = X^T[d][pair]
    for (int i = 0; i < 6; ++i) {
        int slot = i * 256 + tid;
        int tt = slot / 384, rem = slot % 384;
        int c = rem / 64, l = rem % 64;
        int dt = c % 3, par = c / 3;
        int d = 32 * dt + (l & 31);
        int p0 = 32 * tt + 16 * par + 8 * (l >> 5);
        bf16x8 v;
        #pragma unroll
        for (int j = 0; j < 8; ++j)
            v[j] = (__bf16)(float)sxh[(p0 + j) * PAP + d];
        *(bf16x8*)&Xf[((long)blockIdx.x * 4 + tt) * XFT + c * 512 + l * 8] = v;
    }
}

// ---------------------------------------------------------------------------
// Flash: grid = 32 qblocks * NS; 256 thr = 4 waves x 64 q (qt=2). No LDS, no
// barriers. S carried across iterations; K reg-dbuf, X single-buffer.
// Partials written as BF16, layout [q][NS][68]; col 66 = denominator.
// ---------------------------------------------------------------------------
__global__ __launch_bounds__(256, 2) void flash_kernel(
    const unsigned short* __restrict__ Qh_u, const unsigned short* __restrict__ Af_u,
    const unsigned short* __restrict__ Xf_u, unsigned short* __restrict__ Part_u) {
    const _Float16* Qh = (const _Float16*)Qh_u;
    const _Float16* Af = (const _Float16*)Af_u;
    const __bf16*   Xf = (const __bf16*)Xf_u;
    __bf16* Part = (__bf16*)Part_u;

    const int tid = threadIdx.x;
    const int lane = tid & 63, wave = tid >> 6;
    const int l31 = lane & 31, h = lane >> 5;
    const int qb = blockIdx.x / NS, ns = blockIdx.x % NS;
    const int tiles = NTILES / NS;            // 128
    const int qbase = qb * 256 + wave * 64;

    const _Float16* kf = Af + (long)(ns * tiles) * KFT + lane * 8;
    const __bf16*   xf = Xf + (long)(ns * tiles) * XFT + lane * 8;

    f16x8 aQ[2][5];
    #pragma unroll
    for (int qt = 0; qt < 2; ++qt)
        #pragma unroll
        for (int kk = 0; kk < 5; ++kk)
            aQ[qt][kk] = *(const f16x8*)&Qh[(long)(qbase + qt * 32 + l31) * QPITCH + kk * 16 + h * 8];

    f32x16 o[2][3] = {};
    f16x8  kA[5], kB[5];
    bf16x8 xR[6];
    f32x16 s0, s1;

    #pragma unroll
    for (int kk = 0; kk < 5; ++kk) kA[kk] = *(const f16x8*)(kf + kk * 512);
    #pragma unroll
    for (int c = 0; c < 6; ++c)    xR[c]  = *(const bf16x8*)(xf + c * 512);
    #pragma unroll
    for (int kk = 0; kk < 5; ++kk) kB[kk] = *(const f16x8*)(kf + KFT + kk * 512);
    {
        f32x16 a = {}, b = {};
        #pragma unroll
        for (int kk = 0; kk < 5; ++kk) {
            a = mfma_f16(kA[kk], aQ[0][kk], a);
            b = mfma_f16(kA[kk], aQ[1][kk], b);
        }
        s0 = a; s1 = b;
    }

    for (int t = 0; t < tiles; t += 2) {
        pipe_step(t,     tiles, kf, xf, kA, kB, xR, aQ, s0, s1, o);
        pipe_step(t + 1, tiles, kf, xf, kB, kA, xR, aQ, s0, s1, o);
    }

    // epilogue: bf16 partials [q][NS][68]; col 66 = denominator
    #pragma unroll
    for (int qt = 0; qt < 2; ++qt)
        #pragma unroll
        for (int dt = 0; dt < 3; ++dt)
            #pragma unroll
            for (int r = 0; r < 16; ++r) {
                int row = (r & 3) + 8 * (r >> 2) + 4 * h;
                int q = qbase + qt * 32 + row;
                int d = dt * 32 + l31;
                if (d < DIM + 1)
                    Part[((long)q * NS + ns) * PARTP + d] = (__bf16)o[qt][dt][r];
            }
}

// ---------------------------------------------------------------------------
// Combine: out[q][d] = sum_s Part[q][s][d] / sum_s Part[q][s][66]
// Part rows for one q are contiguous (NS*136 B).
// ---------------------------------------------------------------------------
__global__ __launch_bounds__(256) void combine_kernel(
    const unsigned short* __restrict__ Part_u, float* __restrict__ out) {
    const __bf16* Part = (const __bf16*)Part_u;
    int q = blockIdx.x * 2 + (threadIdx.x >> 7);
    int d = threadIdx.x & 127;
    if (d >= DIM) return;
    const __bf16* base = Part + (long)q * NS * PARTP;
    float num = 0.f, den = 0.f;
    #pragma unroll 4
    for (int s = 0; s < NS; ++s) {
        num += (float)base[s * PARTP + d];
        den += (float)base[s * PARTP + DIM];
    }
    out[(long)q * DIM + d] = num / den;
}

// ---------------------------------------------------------------------------
// Workspace: Qh @0 (1,310,720 B) ; Af @1,310,720 (10,485,760 B) ;
//            Xf @11,796,480 (12,582,912 B) ; Part @24,379,392 (17,825,792 B)
// ---------------------------------------------------------------------------
extern "C" void kernel_launch(void* const* d_in, const int* in_sizes, int n_in,
                              void* d_out, int out_size, void* d_ws, size_t ws_size,
                              hipStream_t stream) {
    const float* x     = (const float*)d_in[0];
    const float* query = (const float*)d_in[1];
    const float* Wk    = (const float*)d_in[2];
    float* out = (float*)d_out;
    char* ws = (char*)d_ws;

    unsigned short* Qh   = (unsigned short*)(ws + 0);
    unsigned short* Af   = (unsigned short*)(ws + 1310720);
    unsigned short* Xf   = (unsigned short*)(ws + 11796480);
    unsigned short* Part = (unsigned short*)(ws + 24379392);

    prep_kernel<<<512 + NUM_Q / 128, 256, 0, stream>>>(x, query, Wk, Af, Xf, Qh);
    flash_kernel<<<(NUM_Q / 256) * NS, 256, 0, stream>>>(Qh, Af, Xf, Part);
    combine_kernel<<<NUM_Q / 2, 256, 0, stream>>>(Part, out);
}